// Round 1
// baseline (14484.082 us; speedup 1.0000x reference)
//
#include <hip/hip_runtime.h>
#include <hip/hip_cooperative_groups.h>
#include <cmath>

namespace cg = cooperative_groups;

#define TT 64
#define BB 64
#define SS 512
#define AA 16
#define RR 64
#define HH 32

// ws layout in floats
#define WS_TR   0                         // transition [A][S][S] = 4194304
#define WS_AT   4194304                   // alpha_a transposed [T][A][B] = 65536
#define WS_PDF  (WS_AT + 65536)           // tau_pdf [32]
#define WS_BELT (WS_PDF + 32)             // bel transposed [S][B] = 32768
#define WS_PART (WS_BELT + 32768)         // partial [16][B][S] = 524288

// ---------------- transition: T[k,i,j] = softmax_j( (u_i - 2 (u_i.vn_k) vn_k) . u_j )
__global__ __launch_bounds__(256) void k_transition(const float* __restrict__ u,
                                                    const float* __restrict__ v,
                                                    float* __restrict__ Tr) {
  int bx = blockIdx.x;              // 0..8191 : k*512 + i
  int k = bx >> 9, i = bx & 511;
  __shared__ float vk[RR], urot[RR], red[256];
  __shared__ float scale_s;
  int tid = threadIdx.x;
  if (tid < RR) { vk[tid] = v[k*RR + tid]; urot[tid] = u[i*RR + tid]; }
  __syncthreads();
  if (tid == 0) {
    float n2 = 0.f, dt = 0.f;
    for (int m = 0; m < RR; m++) { n2 += vk[m]*vk[m]; dt += urot[m]*vk[m]; }
    scale_s = 2.f * dt / n2;
  }
  __syncthreads();
  if (tid < RR) urot[tid] = urot[tid] - scale_s * vk[tid];
  __syncthreads();
  float wv[2];
  for (int rr = 0; rr < 2; rr++) {
    int j = tid + rr*256;
    const float* uj = u + (size_t)j*RR;
    float acc = 0.f;
    #pragma unroll
    for (int m = 0; m < RR; m += 4) {
      float4 u4 = *(const float4*)(uj + m);
      acc += urot[m]*u4.x + urot[m+1]*u4.y + urot[m+2]*u4.z + urot[m+3]*u4.w;
    }
    wv[rr] = acc;
  }
  float lm = fmaxf(wv[0], wv[1]);
  red[tid] = lm; __syncthreads();
  for (int s = 128; s > 0; s >>= 1) { if (tid < s) red[tid] = fmaxf(red[tid], red[tid+s]); __syncthreads(); }
  float mx = red[0]; __syncthreads();
  float e0 = expf(wv[0]-mx), e1 = expf(wv[1]-mx);
  red[tid] = e0 + e1; __syncthreads();
  for (int s = 128; s > 0; s >>= 1) { if (tid < s) red[tid] += red[tid+s]; __syncthreads(); }
  float inv = 1.f / red[0];
  float* o = Tr + (size_t)bx * SS;
  o[tid] = e0*inv; o[tid+256] = e1*inv;
}

// ---------------- alpha_a = softmax(logp_u, -1), stored transposed [T][A][B]
__global__ __launch_bounds__(256) void k_alpha_a(const float* __restrict__ lpu,
                                                 float* __restrict__ aT) {
  int idx = blockIdx.x*256 + threadIdx.x;   // t*64+n, 4096 total
  int t = idx >> 6, n = idx & 63;
  const float* x = lpu + (size_t)idx * AA;
  float xs[AA]; float m = -1e30f;
  #pragma unroll
  for (int k = 0; k < AA; k++) { xs[k] = x[k]; m = fmaxf(m, xs[k]); }
  float s = 0.f;
  #pragma unroll
  for (int k = 0; k < AA; k++) { xs[k] = expf(xs[k]-m); s += xs[k]; }
  float inv = 1.f/s;
  #pragma unroll
  for (int k = 0; k < AA; k++) aT[t*(AA*BB) + k*BB + n] = xs[k]*inv;
}

// ---------------- normalized Poisson pmf over k=1..H with rate=softplus(tau)
__global__ void k_taupdf(const float* __restrict__ tau, float* __restrict__ pdf) {
  __shared__ float pl[HH]; __shared__ float ss;
  int tid = threadIdx.x;
  float rate = log1pf(expf(tau[0]));
  if (tid < HH) {
    float kk = (float)(tid+1);
    pl[tid] = expf(kk*logf(rate) - rate - lgammaf(kk+1.f));
  }
  __syncthreads();
  if (tid == 0) { float s = 0.f; for (int h = 0; h < HH; h++) s += pl[h]; ss = 1.f/s; }
  __syncthreads();
  if (tid < HH) pdf[tid] = pl[tid]*ss;
}

// ---------------- belT[i][n] = b[n][i]
__global__ __launch_bounds__(256) void k_belinit(const float* __restrict__ b,
                                                 float* __restrict__ belT) {
  int idx = blockIdx.x*256 + threadIdx.x;   // < 32768
  int i = idx >> 6, n = idx & 63;
  belT[idx] = b[(size_t)n*SS + i];
}

// ---------------- the sequential scan: cooperative, 512 blocks x 256 thr
// block = (jc 0..31 [16 j's], kc 0..15 [1 action k]); thread = (n = tid&63, jq = tid>>6 [4 j's])
__global__ __launch_bounds__(256) void k_scan(const float* __restrict__ Tr,
                                              const float* __restrict__ lpo,
                                              const float* __restrict__ aT,
                                              float* __restrict__ belT,
                                              float* __restrict__ partial,
                                              float* __restrict__ alpha_b) {
  cg::grid_group grid = cg::this_grid();
  __shared__ float bel_s[128*64];   // 32 KB stage: 128 i x 64 n
  __shared__ float red[256];
  int tid = threadIdx.x, bx = blockIdx.x;
  int jc = bx & 31, kc = bx >> 5;
  int n = tid & 63, jq = tid >> 6;
  int j0 = jc*16 + jq*4;
  const float* TrK = Tr + ((size_t)kc * SS) * SS + j0;   // + i*SS

  for (int t = 0; t < TT; t++) {
    float av = aT[t*(AA*BB) + kc*BB + n];
    float acc0=0.f, acc1=0.f, acc2=0.f, acc3=0.f;
    for (int st = 0; st < 4; st++) {
      __syncthreads();
      #pragma unroll
      for (int l = 0; l < 32; l++) {
        int idx = l*256 + tid;
        bel_s[idx] = belT[st*8192 + idx];
      }
      __syncthreads();
      const float* p = TrK + (size_t)(st*128) * SS;
      #pragma unroll 4
      for (int ii = 0; ii < 128; ii++) {
        float bw = av * bel_s[ii*64 + n];
        float4 tv = *(const float4*)p;
        acc0 = fmaf(bw, tv.x, acc0);
        acc1 = fmaf(bw, tv.y, acc1);
        acc2 = fmaf(bw, tv.z, acc2);
        acc3 = fmaf(bw, tv.w, acc3);
        p += SS;
      }
    }
    float4 pv; pv.x = acc0; pv.y = acc1; pv.z = acc2; pv.w = acc3;
    *(float4*)(partial + (size_t)kc*32768 + n*512 + j0) = pv;
    grid.sync();

    if (bx < 64) {   // phase B: block bx owns batch row nn
      int nn = bx;
      float sr[2];
      #pragma unroll
      for (int rr = 0; rr < 2; rr++) {
        int j = tid + rr*256;
        float s = 0.f;
        #pragma unroll
        for (int c = 0; c < 16; c++) s += partial[(size_t)c*32768 + nn*512 + j];
        sr[rr] = logf(s + 1e-6f) + lpo[((size_t)t*BB + nn)*SS + j];
      }
      float lm = fmaxf(sr[0], sr[1]);
      red[tid] = lm; __syncthreads();
      for (int s2 = 128; s2 > 0; s2 >>= 1) { if (tid < s2) red[tid] = fmaxf(red[tid], red[tid+s2]); __syncthreads(); }
      float mx = red[0]; __syncthreads();
      float e0 = expf(sr[0]-mx), e1 = expf(sr[1]-mx);
      red[tid] = e0 + e1; __syncthreads();
      for (int s2 = 128; s2 > 0; s2 >>= 1) { if (tid < s2) red[tid] += red[tid+s2]; __syncthreads(); }
      float inv = 1.f/red[0];
      float b0 = e0*inv, b1 = e1*inv;
      size_t ob = ((size_t)t*BB + nn)*SS;
      alpha_b[ob + tid]       = b0;
      alpha_b[ob + tid + 256] = b1;
      belT[(size_t)tid*64 + nn]       = b0;
      belT[(size_t)(tid+256)*64 + nn] = b1;
    }
    grid.sync();
  }
}

// ---------------- plan() for all T at once: block = (n, 16-t chunk)
__global__ __launch_bounds__(256) void k_pi(const float* __restrict__ alpha_b,
                                            const float* __restrict__ value,
                                            const float* __restrict__ pdf,
                                            float* __restrict__ alpha_pi) {
  __shared__ float Ab_l[16*512];   // 32 KB
  __shared__ float lg[16*256];     // 16 KB
  __shared__ float pi_l[256];
  __shared__ float pdf_l[HH];
  int tid = threadIdx.x, bx = blockIdx.x;
  int n = bx & 63, tc = bx >> 6;   // tc 0..3
  int t0 = tc*16;
  if (tid < HH) pdf_l[tid] = pdf[tid];
  #pragma unroll
  for (int l = 0; l < 32; l++) {
    int idx = l*256 + tid;
    int tt = idx >> 9, i = idx & 511;
    Ab_l[idx] = alpha_b[(((size_t)(t0+tt))*BB + n)*SS + i];
  }
  __syncthreads();
  for (int r = 0; r < 2; r++) {
    int hk = r*256 + tid;
    int h = hk >> 4, k = hk & 15;
    const float* Vrow = value + (((size_t)h*BB + n)*AA + k)*SS;
    float acc[16];
    #pragma unroll
    for (int tt = 0; tt < 16; tt++) acc[tt] = 0.f;
    for (int i = 0; i < SS; i += 4) {
      float4 v4 = *(const float4*)(Vrow + i);
      #pragma unroll
      for (int tt = 0; tt < 16; tt++) {
        float4 ab = *(const float4*)&Ab_l[tt*512 + i];
        acc[tt] = fmaf(v4.x, ab.x, acc[tt]);
        acc[tt] = fmaf(v4.y, ab.y, acc[tt]);
        acc[tt] = fmaf(v4.z, ab.z, acc[tt]);
        acc[tt] = fmaf(v4.w, ab.w, acc[tt]);
      }
    }
    #pragma unroll
    for (int tt = 0; tt < 16; tt++) lg[tt*256 + tid] = acc[tt];
    __syncthreads();
    {
      int tt = tid & 15, hh = tid >> 4;
      int h2 = r*16 + hh;
      float* row = &lg[tt*256 + hh*16];
      float m = row[0];
      #pragma unroll
      for (int k2 = 1; k2 < 16; k2++) m = fmaxf(m, row[k2]);
      float e[16]; float s = 0.f;
      #pragma unroll
      for (int k2 = 0; k2 < 16; k2++) { e[k2] = expf(row[k2]-m); s += e[k2]; }
      float w = pdf_l[h2] / s;
      #pragma unroll
      for (int k2 = 0; k2 < 16; k2++) row[k2] = e[k2]*w;
    }
    __syncthreads();
    {
      int tt = tid >> 4, k2 = tid & 15;
      float s = 0.f;
      #pragma unroll
      for (int hh = 0; hh < 16; hh++) s += lg[tt*256 + hh*16 + k2];
      if (r == 0) pi_l[tid] = s; else pi_l[tid] += s;
    }
    __syncthreads();
  }
  int tt = tid >> 4, k2 = tid & 15;
  alpha_pi[(((size_t)(t0+tt))*BB + n)*AA + k2] = pi_l[tid];
}

extern "C" void kernel_launch(void* const* d_in, const int* in_sizes, int n_in,
                              void* d_out, int out_size, void* d_ws, size_t ws_size,
                              hipStream_t stream) {
  const float* lpo   = (const float*)d_in[0];   // [T,B,S]
  const float* lpu   = (const float*)d_in[1];   // [T,B,A]
  const float* value = (const float*)d_in[2];   // [H,B,A,S]
  const float* b     = (const float*)d_in[3];   // [B,S]
  const float* u     = (const float*)d_in[4];   // [S,R]
  const float* v     = (const float*)d_in[5];   // [A,R]
  const float* tau   = (const float*)d_in[6];   // [1,1]
  float* out = (float*)d_out;
  float* ws  = (float*)d_ws;

  float* Tr      = ws + WS_TR;
  float* aT      = ws + WS_AT;
  float* pdf     = ws + WS_PDF;
  float* belT    = ws + WS_BELT;
  float* partial = ws + WS_PART;

  hipLaunchKernelGGL(k_transition, dim3(AA*SS), dim3(256), 0, stream, u, v, Tr);
  hipLaunchKernelGGL(k_alpha_a,    dim3(16),    dim3(256), 0, stream, lpu, aT);
  hipLaunchKernelGGL(k_taupdf,     dim3(1),     dim3(64),  0, stream, tau, pdf);
  hipLaunchKernelGGL(k_belinit,    dim3(128),   dim3(256), 0, stream, b, belT);

  float* alpha_b = out;
  void* args[6];
  args[0] = (void*)&Tr;
  args[1] = (void*)&lpo;
  args[2] = (void*)&aT;
  args[3] = (void*)&belT;
  args[4] = (void*)&partial;
  args[5] = (void*)&alpha_b;
  hipLaunchCooperativeKernel(k_scan, dim3(512), dim3(256), args, 0, stream);

  float* alpha_pi = out + (size_t)TT*BB*SS;
  hipLaunchKernelGGL(k_pi, dim3(256), dim3(256), 0, stream, out, value, pdf, alpha_pi);
}

// Round 2
// 11309.334 us; speedup vs baseline: 1.2807x; 1.2807x over previous
//
#include <hip/hip_runtime.h>
#include <hip/hip_cooperative_groups.h>
#include <cmath>

namespace cg = cooperative_groups;

#define TT 64
#define BB 64
#define SS 512
#define AA 16
#define RR 64
#define HH 32

// ws layout in floats
#define WS_TR   0                         // transition [A][S][S] = 4194304
#define WS_AT   4194304                   // alpha_a transposed [T][A][B] = 65536
#define WS_PDF  (WS_AT + 65536)           // tau_pdf [32]
#define WS_BELT (WS_PDF + 32)             // bel transposed [S][B] = 32768
#define WS_PART (WS_BELT + 32768)         // partial [16][B][S] = 524288
#define WS_BAR  (WS_PART + 524288)        // barrier counter (1 uint)

#define AGENT_SCOPE __HIP_MEMORY_SCOPE_AGENT

__device__ __forceinline__ float aload(const float* p) {
  return __hip_atomic_load(p, __ATOMIC_RELAXED, AGENT_SCOPE);
}
__device__ __forceinline__ void astore(float* p, float v) {
  __hip_atomic_store(p, v, __ATOMIC_RELAXED, AGENT_SCOPE);
}

// grid barrier: monotonic epoch counter, release-arrive, relaxed spin.
// NO acquire fence -> no buffer_inv -> per-XCD L2 keeps read-only Tr hot.
__device__ __forceinline__ void gbar(unsigned* cnt, unsigned target) {
  __syncthreads();   // all threads of block done (their vmcnt drained by syncthreads)
  if (threadIdx.x == 0) {
    __hip_atomic_fetch_add(cnt, 1u, __ATOMIC_RELEASE, AGENT_SCOPE);
    while (__hip_atomic_load(cnt, __ATOMIC_RELAXED, AGENT_SCOPE) < target) {
      __builtin_amdgcn_s_sleep(1);
    }
  }
  __syncthreads();
}

// ---------------- transition: T[k,i,j] = softmax_j( (u_i - 2 (u_i.vn_k) vn_k) . u_j )
__global__ __launch_bounds__(256) void k_transition(const float* __restrict__ u,
                                                    const float* __restrict__ v,
                                                    float* __restrict__ Tr) {
  int bx = blockIdx.x;              // 0..8191 : k*512 + i
  int k = bx >> 9, i = bx & 511;
  __shared__ float vk[RR], urot[RR], red[256];
  __shared__ float scale_s;
  int tid = threadIdx.x;
  if (tid < RR) { vk[tid] = v[k*RR + tid]; urot[tid] = u[i*RR + tid]; }
  __syncthreads();
  if (tid == 0) {
    float n2 = 0.f, dt = 0.f;
    for (int m = 0; m < RR; m++) { n2 += vk[m]*vk[m]; dt += urot[m]*vk[m]; }
    scale_s = 2.f * dt / n2;
  }
  __syncthreads();
  if (tid < RR) urot[tid] = urot[tid] - scale_s * vk[tid];
  __syncthreads();
  float wv[2];
  for (int rr = 0; rr < 2; rr++) {
    int j = tid + rr*256;
    const float* uj = u + (size_t)j*RR;
    float acc = 0.f;
    #pragma unroll
    for (int m = 0; m < RR; m += 4) {
      float4 u4 = *(const float4*)(uj + m);
      acc += urot[m]*u4.x + urot[m+1]*u4.y + urot[m+2]*u4.z + urot[m+3]*u4.w;
    }
    wv[rr] = acc;
  }
  float lm = fmaxf(wv[0], wv[1]);
  red[tid] = lm; __syncthreads();
  for (int s = 128; s > 0; s >>= 1) { if (tid < s) red[tid] = fmaxf(red[tid], red[tid+s]); __syncthreads(); }
  float mx = red[0]; __syncthreads();
  float e0 = expf(wv[0]-mx), e1 = expf(wv[1]-mx);
  red[tid] = e0 + e1; __syncthreads();
  for (int s = 128; s > 0; s >>= 1) { if (tid < s) red[tid] += red[tid+s]; __syncthreads(); }
  float inv = 1.f / red[0];
  float* o = Tr + (size_t)bx * SS;
  o[tid] = e0*inv; o[tid+256] = e1*inv;
}

// ---------------- alpha_a = softmax(logp_u, -1), stored transposed [T][A][B]
__global__ __launch_bounds__(256) void k_alpha_a(const float* __restrict__ lpu,
                                                 float* __restrict__ aT) {
  int idx = blockIdx.x*256 + threadIdx.x;   // t*64+n, 4096 total
  int t = idx >> 6, n = idx & 63;
  const float* x = lpu + (size_t)idx * AA;
  float xs[AA]; float m = -1e30f;
  #pragma unroll
  for (int k = 0; k < AA; k++) { xs[k] = x[k]; m = fmaxf(m, xs[k]); }
  float s = 0.f;
  #pragma unroll
  for (int k = 0; k < AA; k++) { xs[k] = expf(xs[k]-m); s += xs[k]; }
  float inv = 1.f/s;
  #pragma unroll
  for (int k = 0; k < AA; k++) aT[t*(AA*BB) + k*BB + n] = xs[k]*inv;
}

// ---------------- normalized Poisson pmf over k=1..H with rate=softplus(tau)
__global__ void k_taupdf(const float* __restrict__ tau, float* __restrict__ pdf) {
  __shared__ float pl[HH]; __shared__ float ss;
  int tid = threadIdx.x;
  float rate = log1pf(expf(tau[0]));
  if (tid < HH) {
    float kk = (float)(tid+1);
    pl[tid] = expf(kk*logf(rate) - rate - lgammaf(kk+1.f));
  }
  __syncthreads();
  if (tid == 0) { float s = 0.f; for (int h = 0; h < HH; h++) s += pl[h]; ss = 1.f/s; }
  __syncthreads();
  if (tid < HH) pdf[tid] = pl[tid]*ss;
}

// ---------------- belT[i][n] = b[n][i]; also zero the barrier counter
__global__ __launch_bounds__(256) void k_belinit(const float* __restrict__ b,
                                                 float* __restrict__ belT,
                                                 unsigned* __restrict__ bar) {
  int idx = blockIdx.x*256 + threadIdx.x;   // < 32768
  int i = idx >> 6, n = idx & 63;
  belT[idx] = b[(size_t)n*SS + i];
  if (idx == 0) *bar = 0u;
}

// ---------------- the sequential scan: 512 blocks x 256 thr, custom barrier
// block = (jc 0..31 [16 j's], kc 0..15 [1 action k]); thread = (n = tid&63, jq = tid>>6 [4 j's])
__global__ __launch_bounds__(256) void k_scan(const float* __restrict__ Tr,
                                              const float* __restrict__ lpo,
                                              const float* __restrict__ aT,
                                              float* __restrict__ belT,
                                              float* __restrict__ partial,
                                              float* __restrict__ alpha_b,
                                              unsigned* __restrict__ bar) {
  __shared__ float bel_s[128*64];   // 32 KB stage: 128 i x 64 n
  __shared__ float red[256];
  int tid = threadIdx.x, bx = blockIdx.x;
  int jc = bx & 31, kc = bx >> 5;
  int n = tid & 63, jq = tid >> 6;
  int j0 = jc*16 + jq*4;
  const float* TrK = Tr + ((size_t)kc * SS) * SS + j0;   // + i*SS
  unsigned tgt = 0;

  for (int t = 0; t < TT; t++) {
    float av = aT[t*(AA*BB) + kc*BB + n];
    float acc0=0.f, acc1=0.f, acc2=0.f, acc3=0.f;
    for (int st = 0; st < 4; st++) {
      __syncthreads();
      {
        float tmp[32];
        #pragma unroll
        for (int l = 0; l < 32; l++) tmp[l] = aload(belT + st*8192 + l*256 + tid);
        #pragma unroll
        for (int l = 0; l < 32; l++) bel_s[l*256 + tid] = tmp[l];
      }
      __syncthreads();
      const float* p = TrK + (size_t)(st*128) * SS;
      #pragma unroll 8
      for (int ii = 0; ii < 128; ii++) {
        float bw = av * bel_s[ii*64 + n];
        float4 tv = *(const float4*)p;
        acc0 = fmaf(bw, tv.x, acc0);
        acc1 = fmaf(bw, tv.y, acc1);
        acc2 = fmaf(bw, tv.z, acc2);
        acc3 = fmaf(bw, tv.w, acc3);
        p += SS;
      }
    }
    {
      float* pp = partial + (size_t)kc*32768 + n*512 + j0;
      astore(pp+0, acc0); astore(pp+1, acc1); astore(pp+2, acc2); astore(pp+3, acc3);
    }
    tgt += 512; gbar(bar, tgt);

    if (bx < 64) {   // phase B: block bx owns batch row nn
      int nn = bx;
      float sr[2];
      #pragma unroll
      for (int rr = 0; rr < 2; rr++) {
        int j = tid + rr*256;
        float tmp[16];
        #pragma unroll
        for (int c = 0; c < 16; c++) tmp[c] = aload(partial + (size_t)c*32768 + nn*512 + j);
        float s = 0.f;
        #pragma unroll
        for (int c = 0; c < 16; c++) s += tmp[c];
        sr[rr] = logf(s + 1e-6f) + lpo[((size_t)t*BB + nn)*SS + j];
      }
      float lm = fmaxf(sr[0], sr[1]);
      red[tid] = lm; __syncthreads();
      for (int s2 = 128; s2 > 0; s2 >>= 1) { if (tid < s2) red[tid] = fmaxf(red[tid], red[tid+s2]); __syncthreads(); }
      float mx = red[0]; __syncthreads();
      float e0 = expf(sr[0]-mx), e1 = expf(sr[1]-mx);
      red[tid] = e0 + e1; __syncthreads();
      for (int s2 = 128; s2 > 0; s2 >>= 1) { if (tid < s2) red[tid] += red[tid+s2]; __syncthreads(); }
      float inv = 1.f/red[0];
      float b0 = e0*inv, b1 = e1*inv;
      size_t ob = ((size_t)t*BB + nn)*SS;
      alpha_b[ob + tid]       = b0;     // output only: normal store, visible at kernel end
      alpha_b[ob + tid + 256] = b1;
      astore(belT + (size_t)tid*64 + nn,       b0);   // carry: agent-scope
      astore(belT + (size_t)(tid+256)*64 + nn, b1);
    }
    tgt += 512; gbar(bar, tgt);
  }
}

// ---------------- plan() for all T at once: block = (n, 16-t chunk)
__global__ __launch_bounds__(256) void k_pi(const float* __restrict__ alpha_b,
                                            const float* __restrict__ value,
                                            const float* __restrict__ pdf,
                                            float* __restrict__ alpha_pi) {
  __shared__ float Ab_l[16*512];   // 32 KB
  __shared__ float lg[16*256];     // 16 KB
  __shared__ float pi_l[256];
  __shared__ float pdf_l[HH];
  int tid = threadIdx.x, bx = blockIdx.x;
  int n = bx & 63, tc = bx >> 6;   // tc 0..3
  int t0 = tc*16;
  if (tid < HH) pdf_l[tid] = pdf[tid];
  #pragma unroll
  for (int l = 0; l < 32; l++) {
    int idx = l*256 + tid;
    int tt = idx >> 9, i = idx & 511;
    Ab_l[idx] = alpha_b[(((size_t)(t0+tt))*BB + n)*SS + i];
  }
  __syncthreads();
  for (int r = 0; r < 2; r++) {
    int hk = r*256 + tid;
    int h = hk >> 4, k = hk & 15;
    const float* Vrow = value + (((size_t)h*BB + n)*AA + k)*SS;
    float acc[16];
    #pragma unroll
    for (int tt = 0; tt < 16; tt++) acc[tt] = 0.f;
    for (int i = 0; i < SS; i += 4) {
      float4 v4 = *(const float4*)(Vrow + i);
      #pragma unroll
      for (int tt = 0; tt < 16; tt++) {
        float4 ab = *(const float4*)&Ab_l[tt*512 + i];
        acc[tt] = fmaf(v4.x, ab.x, acc[tt]);
        acc[tt] = fmaf(v4.y, ab.y, acc[tt]);
        acc[tt] = fmaf(v4.z, ab.z, acc[tt]);
        acc[tt] = fmaf(v4.w, ab.w, acc[tt]);
      }
    }
    #pragma unroll
    for (int tt = 0; tt < 16; tt++) lg[tt*256 + tid] = acc[tt];
    __syncthreads();
    {
      int tt = tid & 15, hh = tid >> 4;
      int h2 = r*16 + hh;
      float* row = &lg[tt*256 + hh*16];
      float m = row[0];
      #pragma unroll
      for (int k2 = 1; k2 < 16; k2++) m = fmaxf(m, row[k2]);
      float e[16]; float s = 0.f;
      #pragma unroll
      for (int k2 = 0; k2 < 16; k2++) { e[k2] = expf(row[k2]-m); s += e[k2]; }
      float w = pdf_l[h2] / s;
      #pragma unroll
      for (int k2 = 0; k2 < 16; k2++) row[k2] = e[k2]*w;
    }
    __syncthreads();
    {
      int tt = tid >> 4, k2 = tid & 15;
      float s = 0.f;
      #pragma unroll
      for (int hh = 0; hh < 16; hh++) s += lg[tt*256 + hh*16 + k2];
      if (r == 0) pi_l[tid] = s; else pi_l[tid] += s;
    }
    __syncthreads();
  }
  int tt = tid >> 4, k2 = tid & 15;
  alpha_pi[(((size_t)(t0+tt))*BB + n)*AA + k2] = pi_l[tid];
}

extern "C" void kernel_launch(void* const* d_in, const int* in_sizes, int n_in,
                              void* d_out, int out_size, void* d_ws, size_t ws_size,
                              hipStream_t stream) {
  const float* lpo   = (const float*)d_in[0];   // [T,B,S]
  const float* lpu   = (const float*)d_in[1];   // [T,B,A]
  const float* value = (const float*)d_in[2];   // [H,B,A,S]
  const float* b     = (const float*)d_in[3];   // [B,S]
  const float* u     = (const float*)d_in[4];   // [S,R]
  const float* v     = (const float*)d_in[5];   // [A,R]
  const float* tau   = (const float*)d_in[6];   // [1,1]
  float* out = (float*)d_out;
  float* ws  = (float*)d_ws;

  float* Tr      = ws + WS_TR;
  float* aT      = ws + WS_AT;
  float* pdf     = ws + WS_PDF;
  float* belT    = ws + WS_BELT;
  float* partial = ws + WS_PART;
  unsigned* bar  = (unsigned*)(ws + WS_BAR);

  hipLaunchKernelGGL(k_transition, dim3(AA*SS), dim3(256), 0, stream, u, v, Tr);
  hipLaunchKernelGGL(k_alpha_a,    dim3(16),    dim3(256), 0, stream, lpu, aT);
  hipLaunchKernelGGL(k_taupdf,     dim3(1),     dim3(64),  0, stream, tau, pdf);
  hipLaunchKernelGGL(k_belinit,    dim3(128),   dim3(256), 0, stream, b, belT, bar);

  float* alpha_b = out;
  void* args[7];
  args[0] = (void*)&Tr;
  args[1] = (void*)&lpo;
  args[2] = (void*)&aT;
  args[3] = (void*)&belT;
  args[4] = (void*)&partial;
  args[5] = (void*)&alpha_b;
  args[6] = (void*)&bar;
  hipLaunchCooperativeKernel(k_scan, dim3(512), dim3(256), args, 0, stream);

  float* alpha_pi = out + (size_t)TT*BB*SS;
  hipLaunchKernelGGL(k_pi, dim3(256), dim3(256), 0, stream, out, value, pdf, alpha_pi);
}

// Round 3
// 2770.981 us; speedup vs baseline: 5.2271x; 4.0813x over previous
//
#include <hip/hip_runtime.h>
#include <cmath>

#define TT 64
#define BB 64
#define SS 512
#define AA 16
#define RR 64
#define HH 32

// ws layout in floats
#define WS_TR   0                         // transition [A][S][S] = 4194304
#define WS_AT   4194304                   // alpha_a transposed [T][A][B] = 65536
#define WS_PDF  (WS_AT + 65536)           // tau_pdf [32]
#define WS_BELT (WS_PDF + 32)             // bel transposed [S][B] = 32768
#define WS_PART (WS_BELT + 32768)         // partial [16][B][S] = 524288

// ---------------- transition: T[k,i,j] = softmax_j( (u_i - 2 (u_i.vn_k) vn_k) . u_j )
__global__ __launch_bounds__(256) void k_transition(const float* __restrict__ u,
                                                    const float* __restrict__ v,
                                                    float* __restrict__ Tr) {
  int bx = blockIdx.x;              // 0..8191 : k*512 + i
  int k = bx >> 9, i = bx & 511;
  __shared__ float vk[RR], urot[RR], red[256];
  __shared__ float scale_s;
  int tid = threadIdx.x;
  if (tid < RR) { vk[tid] = v[k*RR + tid]; urot[tid] = u[i*RR + tid]; }
  __syncthreads();
  if (tid == 0) {
    float n2 = 0.f, dt = 0.f;
    for (int m = 0; m < RR; m++) { n2 += vk[m]*vk[m]; dt += urot[m]*vk[m]; }
    scale_s = 2.f * dt / n2;
  }
  __syncthreads();
  if (tid < RR) urot[tid] = urot[tid] - scale_s * vk[tid];
  __syncthreads();
  float wv[2];
  for (int rr = 0; rr < 2; rr++) {
    int j = tid + rr*256;
    const float* uj = u + (size_t)j*RR;
    float acc = 0.f;
    #pragma unroll
    for (int m = 0; m < RR; m += 4) {
      float4 u4 = *(const float4*)(uj + m);
      acc += urot[m]*u4.x + urot[m+1]*u4.y + urot[m+2]*u4.z + urot[m+3]*u4.w;
    }
    wv[rr] = acc;
  }
  float lm = fmaxf(wv[0], wv[1]);
  red[tid] = lm; __syncthreads();
  for (int s = 128; s > 0; s >>= 1) { if (tid < s) red[tid] = fmaxf(red[tid], red[tid+s]); __syncthreads(); }
  float mx = red[0]; __syncthreads();
  float e0 = expf(wv[0]-mx), e1 = expf(wv[1]-mx);
  red[tid] = e0 + e1; __syncthreads();
  for (int s = 128; s > 0; s >>= 1) { if (tid < s) red[tid] += red[tid+s]; __syncthreads(); }
  float inv = 1.f / red[0];
  float* o = Tr + (size_t)bx * SS;
  o[tid] = e0*inv; o[tid+256] = e1*inv;
}

// ---------------- alpha_a = softmax(logp_u, -1), stored transposed [T][A][B]
__global__ __launch_bounds__(256) void k_alpha_a(const float* __restrict__ lpu,
                                                 float* __restrict__ aT) {
  int idx = blockIdx.x*256 + threadIdx.x;   // t*64+n, 4096 total
  int t = idx >> 6, n = idx & 63;
  const float* x = lpu + (size_t)idx * AA;
  float xs[AA]; float m = -1e30f;
  #pragma unroll
  for (int k = 0; k < AA; k++) { xs[k] = x[k]; m = fmaxf(m, xs[k]); }
  float s = 0.f;
  #pragma unroll
  for (int k = 0; k < AA; k++) { xs[k] = expf(xs[k]-m); s += xs[k]; }
  float inv = 1.f/s;
  #pragma unroll
  for (int k = 0; k < AA; k++) aT[t*(AA*BB) + k*BB + n] = xs[k]*inv;
}

// ---------------- normalized Poisson pmf over k=1..H with rate=softplus(tau)
__global__ void k_taupdf(const float* __restrict__ tau, float* __restrict__ pdf) {
  __shared__ float pl[HH]; __shared__ float ss;
  int tid = threadIdx.x;
  float rate = log1pf(expf(tau[0]));
  if (tid < HH) {
    float kk = (float)(tid+1);
    pl[tid] = expf(kk*logf(rate) - rate - lgammaf(kk+1.f));
  }
  __syncthreads();
  if (tid == 0) { float s = 0.f; for (int h = 0; h < HH; h++) s += pl[h]; ss = 1.f/s; }
  __syncthreads();
  if (tid < HH) pdf[tid] = pl[tid]*ss;
}

// ---------------- belT[i][n] = b[n][i]
__global__ __launch_bounds__(256) void k_belinit(const float* __restrict__ b,
                                                 float* __restrict__ belT) {
  int idx = blockIdx.x*256 + threadIdx.x;   // < 32768
  int i = idx >> 6, n = idx & 63;
  belT[idx] = b[(size_t)n*SS + i];
}

// ---------------- one scan step, phase A (the batched tri-linear GEMM)
// 512 blocks: (jc 0..31 [16 j's], kc 0..15); thread = (n = tid&63, jq = tid>>6 [4 j's])
// partial[kc][n][j] = sum_i a[t,n,kc] * bel[i,n] * Tr[kc,i,j]
__global__ __launch_bounds__(256) void k_step_gemm(const float* __restrict__ Tr,
                                                   const float* __restrict__ aT,
                                                   const float* __restrict__ belT,
                                                   float* __restrict__ partial,
                                                   int t) {
  __shared__ float bel_s[128*64];   // 32 KB stage: 128 i x 64 n
  int tid = threadIdx.x, bx = blockIdx.x;
  int jc = bx & 31, kc = bx >> 5;   // jc%8 == XCD -> stable Tr slice per XCD across launches
  int n = tid & 63, jq = tid >> 6;
  int j0 = jc*16 + jq*4;
  const float* TrK = Tr + ((size_t)kc * SS) * SS + j0;   // + i*SS
  float av = aT[t*(AA*BB) + kc*BB + n];
  float acc0=0.f, acc1=0.f, acc2=0.f, acc3=0.f;
  for (int st = 0; st < 4; st++) {
    __syncthreads();
    #pragma unroll
    for (int l = 0; l < 32; l++) bel_s[l*256 + tid] = belT[st*8192 + l*256 + tid];
    __syncthreads();
    const float* p = TrK + (size_t)(st*128) * SS;
    #pragma unroll 8
    for (int ii = 0; ii < 128; ii++) {
      float bw = av * bel_s[ii*64 + n];
      float4 tv = *(const float4*)p;
      acc0 = fmaf(bw, tv.x, acc0);
      acc1 = fmaf(bw, tv.y, acc1);
      acc2 = fmaf(bw, tv.z, acc2);
      acc3 = fmaf(bw, tv.w, acc3);
      p += SS;
    }
  }
  float4 pv; pv.x = acc0; pv.y = acc1; pv.z = acc2; pv.w = acc3;
  *(float4*)(partial + (size_t)kc*32768 + n*512 + j0) = pv;
}

// ---------------- one scan step, phase B: k-reduce + log + lpo + softmax_j
// 64 blocks, block nn owns batch row nn; writes alpha_b[t] and the belT carry
__global__ __launch_bounds__(256) void k_step_softmax(const float* __restrict__ partial,
                                                      const float* __restrict__ lpo,
                                                      float* __restrict__ belT,
                                                      float* __restrict__ alpha_b,
                                                      int t) {
  __shared__ float red[256];
  int tid = threadIdx.x, nn = blockIdx.x;
  float sr[2];
  #pragma unroll
  for (int rr = 0; rr < 2; rr++) {
    int j = tid + rr*256;
    float s = 0.f;
    #pragma unroll
    for (int c = 0; c < 16; c++) s += partial[(size_t)c*32768 + nn*512 + j];
    sr[rr] = logf(s + 1e-6f) + lpo[((size_t)t*BB + nn)*SS + j];
  }
  float lm = fmaxf(sr[0], sr[1]);
  red[tid] = lm; __syncthreads();
  for (int s2 = 128; s2 > 0; s2 >>= 1) { if (tid < s2) red[tid] = fmaxf(red[tid], red[tid+s2]); __syncthreads(); }
  float mx = red[0]; __syncthreads();
  float e0 = expf(sr[0]-mx), e1 = expf(sr[1]-mx);
  red[tid] = e0 + e1; __syncthreads();
  for (int s2 = 128; s2 > 0; s2 >>= 1) { if (tid < s2) red[tid] += red[tid+s2]; __syncthreads(); }
  float inv = 1.f/red[0];
  float b0 = e0*inv, b1 = e1*inv;
  size_t ob = ((size_t)t*BB + nn)*SS;
  alpha_b[ob + tid]       = b0;
  alpha_b[ob + tid + 256] = b1;
  belT[(size_t)tid*64 + nn]       = b0;
  belT[(size_t)(tid+256)*64 + nn] = b1;
}

// ---------------- plan() for all T at once: block = (n, 16-t chunk)
__global__ __launch_bounds__(256) void k_pi(const float* __restrict__ alpha_b,
                                            const float* __restrict__ value,
                                            const float* __restrict__ pdf,
                                            float* __restrict__ alpha_pi) {
  __shared__ float Ab_l[16*512];   // 32 KB
  __shared__ float lg[16*256];     // 16 KB
  __shared__ float pi_l[256];
  __shared__ float pdf_l[HH];
  int tid = threadIdx.x, bx = blockIdx.x;
  int n = bx & 63, tc = bx >> 6;   // tc 0..3
  int t0 = tc*16;
  if (tid < HH) pdf_l[tid] = pdf[tid];
  #pragma unroll
  for (int l = 0; l < 32; l++) {
    int idx = l*256 + tid;
    int tt = idx >> 9, i = idx & 511;
    Ab_l[idx] = alpha_b[(((size_t)(t0+tt))*BB + n)*SS + i];
  }
  __syncthreads();
  for (int r = 0; r < 2; r++) {
    int hk = r*256 + tid;
    int h = hk >> 4, k = hk & 15;
    const float* Vrow = value + (((size_t)h*BB + n)*AA + k)*SS;
    float acc[16];
    #pragma unroll
    for (int tt = 0; tt < 16; tt++) acc[tt] = 0.f;
    for (int i = 0; i < SS; i += 4) {
      float4 v4 = *(const float4*)(Vrow + i);
      #pragma unroll
      for (int tt = 0; tt < 16; tt++) {
        float4 ab = *(const float4*)&Ab_l[tt*512 + i];
        acc[tt] = fmaf(v4.x, ab.x, acc[tt]);
        acc[tt] = fmaf(v4.y, ab.y, acc[tt]);
        acc[tt] = fmaf(v4.z, ab.z, acc[tt]);
        acc[tt] = fmaf(v4.w, ab.w, acc[tt]);
      }
    }
    #pragma unroll
    for (int tt = 0; tt < 16; tt++) lg[tt*256 + tid] = acc[tt];
    __syncthreads();
    {
      int tt = tid & 15, hh = tid >> 4;
      int h2 = r*16 + hh;
      float* row = &lg[tt*256 + hh*16];
      float m = row[0];
      #pragma unroll
      for (int k2 = 1; k2 < 16; k2++) m = fmaxf(m, row[k2]);
      float e[16]; float s = 0.f;
      #pragma unroll
      for (int k2 = 0; k2 < 16; k2++) { e[k2] = expf(row[k2]-m); s += e[k2]; }
      float w = pdf_l[h2] / s;
      #pragma unroll
      for (int k2 = 0; k2 < 16; k2++) row[k2] = e[k2]*w;
    }
    __syncthreads();
    {
      int tt = tid >> 4, k2 = tid & 15;
      float s = 0.f;
      #pragma unroll
      for (int hh = 0; hh < 16; hh++) s += lg[tt*256 + hh*16 + k2];
      if (r == 0) pi_l[tid] = s; else pi_l[tid] += s;
    }
    __syncthreads();
  }
  int tt = tid >> 4, k2 = tid & 15;
  alpha_pi[(((size_t)(t0+tt))*BB + n)*AA + k2] = pi_l[tid];
}

extern "C" void kernel_launch(void* const* d_in, const int* in_sizes, int n_in,
                              void* d_out, int out_size, void* d_ws, size_t ws_size,
                              hipStream_t stream) {
  const float* lpo   = (const float*)d_in[0];   // [T,B,S]
  const float* lpu   = (const float*)d_in[1];   // [T,B,A]
  const float* value = (const float*)d_in[2];   // [H,B,A,S]
  const float* b     = (const float*)d_in[3];   // [B,S]
  const float* u     = (const float*)d_in[4];   // [S,R]
  const float* v     = (const float*)d_in[5];   // [A,R]
  const float* tau   = (const float*)d_in[6];   // [1,1]
  float* out = (float*)d_out;
  float* ws  = (float*)d_ws;

  float* Tr      = ws + WS_TR;
  float* aT      = ws + WS_AT;
  float* pdf     = ws + WS_PDF;
  float* belT    = ws + WS_BELT;
  float* partial = ws + WS_PART;

  hipLaunchKernelGGL(k_transition, dim3(AA*SS), dim3(256), 0, stream, u, v, Tr);
  hipLaunchKernelGGL(k_alpha_a,    dim3(16),    dim3(256), 0, stream, lpu, aT);
  hipLaunchKernelGGL(k_taupdf,     dim3(1),     dim3(64),  0, stream, tau, pdf);
  hipLaunchKernelGGL(k_belinit,    dim3(128),   dim3(256), 0, stream, b, belT);

  float* alpha_b = out;
  for (int t = 0; t < TT; t++) {
    hipLaunchKernelGGL(k_step_gemm,    dim3(512), dim3(256), 0, stream, Tr, aT, belT, partial, t);
    hipLaunchKernelGGL(k_step_softmax, dim3(64),  dim3(256), 0, stream, partial, lpo, belT, alpha_b, t);
  }

  float* alpha_pi = out + (size_t)TT*BB*SS;
  hipLaunchKernelGGL(k_pi, dim3(256), dim3(256), 0, stream, out, value, pdf, alpha_pi);
}

// Round 4
// 2542.513 us; speedup vs baseline: 5.6968x; 1.0899x over previous
//
#include <hip/hip_runtime.h>
#include <cmath>

#define TT 64
#define BB 64
#define SS 512
#define AA 16
#define RR 64
#define HH 32

// ws layout in floats
#define WS_TR   0                         // transition [A][S][S] = 4194304
#define WS_AT   4194304                   // alpha_a transposed [T][A][B] = 65536
#define WS_PDF  (WS_AT + 65536)           // tau_pdf [32]
#define WS_BELT (WS_PDF + 32)             // bel transposed [S][B] = 32768
#define WS_PART (WS_BELT + 32768)         // partial [16 ic][B][S] = 524288

// ---------------- transition, one kernel: Householder + GEMM + row softmax
// grid 512: k = bx>>5 (16), ic = bx&31 (16 i-rows per block)
__global__ __launch_bounds__(256) void k_trans2(const float* __restrict__ u,
                                                const float* __restrict__ v,
                                                float* __restrict__ Tr) {
  int bx = blockIdx.x;
  int k = bx >> 5, ic = bx & 31, i0 = ic * 16;
  __shared__ float urot_s[16][68];   // padded: il-stride hits distinct banks
  __shared__ float ut_s[64][68];     // u^T tile, 16B-aligned rows (68*4=272B)
  __shared__ float w_s[16][516];     // logits tile (516*4=2064B, 16B-aligned)
  int tid = threadIdx.x;
  int lane = tid & 63, wv = tid >> 6;

  // vk and ||vk||^2 (wave-wide)
  float vkm = v[k*RR + lane];
  float n2 = vkm * vkm;
  #pragma unroll
  for (int o = 32; o > 0; o >>= 1) n2 += __shfl_xor(n2, o, 64);

  // urot rows: wave wv handles rows wv*4 .. wv*4+3
  #pragma unroll
  for (int r = 0; r < 4; r++) {
    int il = wv*4 + r;
    float um = u[(size_t)(i0 + il)*RR + lane];
    float dt = um * vkm;
    #pragma unroll
    for (int o = 32; o > 0; o >>= 1) dt += __shfl_xor(dt, o, 64);
    urot_s[il][lane] = um - (2.f * dt / n2) * vkm;
  }

  // w[il][j] = urot[il,:] . u[j,:], j-tiles of 64
  int il = tid >> 4, jl4 = (tid & 15) * 4;
  for (int jt = 0; jt < 8; jt++) {
    __syncthreads();
    // stage u^T tile: ut_s[m][r] = u[jt*64+r][m]
    #pragma unroll
    for (int q = 0; q < 4; q++) {
      int fi = q*256 + tid;            // 0..1023 float4's
      int r = fi >> 4, c4 = (fi & 15) * 4;
      float4 uu = *(const float4*)(u + (size_t)(jt*64 + r)*RR + c4);
      ut_s[c4+0][r] = uu.x; ut_s[c4+1][r] = uu.y;
      ut_s[c4+2][r] = uu.z; ut_s[c4+3][r] = uu.w;
    }
    __syncthreads();
    float4 acc = {0.f, 0.f, 0.f, 0.f};
    #pragma unroll 8
    for (int m = 0; m < 64; m++) {
      float ur = urot_s[il][m];
      float4 uu = *(const float4*)&ut_s[m][jl4];
      acc.x = fmaf(ur, uu.x, acc.x);
      acc.y = fmaf(ur, uu.y, acc.y);
      acc.z = fmaf(ur, uu.z, acc.z);
      acc.w = fmaf(ur, uu.w, acc.w);
    }
    *(float4*)&w_s[il][jt*64 + jl4] = acc;
  }
  __syncthreads();

  // row softmax: wave wv owns rows wv*4 .. wv*4+3, 8 j per lane
  #pragma unroll
  for (int r = 0; r < 4; r++) {
    int ir = wv*4 + r;
    float vals[8]; float mx = -1e30f;
    #pragma unroll
    for (int q = 0; q < 8; q++) { vals[q] = w_s[ir][q*64 + lane]; mx = fmaxf(mx, vals[q]); }
    #pragma unroll
    for (int o = 32; o > 0; o >>= 1) mx = fmaxf(mx, __shfl_xor(mx, o, 64));
    float sm = 0.f;
    #pragma unroll
    for (int q = 0; q < 8; q++) { vals[q] = expf(vals[q] - mx); sm += vals[q]; }
    #pragma unroll
    for (int o = 32; o > 0; o >>= 1) sm += __shfl_xor(sm, o, 64);
    float inv = 1.f / sm;
    #pragma unroll
    for (int q = 0; q < 8; q++)
      Tr[((size_t)k*SS + (i0 + ir))*SS + q*64 + lane] = vals[q] * inv;
  }
}

// ---------------- alpha_a = softmax(logp_u, -1), stored transposed [T][A][B]
__global__ __launch_bounds__(256) void k_alpha_a(const float* __restrict__ lpu,
                                                 float* __restrict__ aT) {
  int idx = blockIdx.x*256 + threadIdx.x;   // t*64+n, 4096 total
  int t = idx >> 6, n = idx & 63;
  const float* x = lpu + (size_t)idx * AA;
  float xs[AA]; float m = -1e30f;
  #pragma unroll
  for (int k = 0; k < AA; k++) { xs[k] = x[k]; m = fmaxf(m, xs[k]); }
  float s = 0.f;
  #pragma unroll
  for (int k = 0; k < AA; k++) { xs[k] = expf(xs[k]-m); s += xs[k]; }
  float inv = 1.f/s;
  #pragma unroll
  for (int k = 0; k < AA; k++) aT[t*(AA*BB) + k*BB + n] = xs[k]*inv;
}

// ---------------- normalized Poisson pmf over k=1..H with rate=softplus(tau)
__global__ void k_taupdf(const float* __restrict__ tau, float* __restrict__ pdf) {
  __shared__ float pl[HH]; __shared__ float ss;
  int tid = threadIdx.x;
  float rate = log1pf(expf(tau[0]));
  if (tid < HH) {
    float kk = (float)(tid+1);
    pl[tid] = expf(kk*logf(rate) - rate - lgammaf(kk+1.f));
  }
  __syncthreads();
  if (tid == 0) { float s = 0.f; for (int h = 0; h < HH; h++) s += pl[h]; ss = 1.f/s; }
  __syncthreads();
  if (tid < HH) pdf[tid] = pl[tid]*ss;
}

// ---------------- belT[i][n] = b[n][i]
__global__ __launch_bounds__(256) void k_belinit(const float* __restrict__ b,
                                                 float* __restrict__ belT) {
  int idx = blockIdx.x*256 + threadIdx.x;   // < 32768
  int i = idx >> 6, n = idx & 63;
  belT[idx] = b[(size_t)n*SS + i];
}

// ---------------- scan phase A: partial[ic][n][j] = sum_{k, i in ic-slice} a[n,k]*bel[i,n]*Tr[k,i,j]
// grid 256: jc = bx&15 (32 j), ic = bx>>4 (32 i). 512 threads: n = tid>>3, jq = tid&7 (4 j).
// Sums over ALL 16 k in-block; j across lanes -> coalesced Tr loads (128B/instr).
__global__ __launch_bounds__(512) void k_step_gemm(const float* __restrict__ Tr,
                                                   const float* __restrict__ aT,
                                                   const float* __restrict__ belT,
                                                   float* __restrict__ partial,
                                                   int t) {
  __shared__ float bel_s[32*64];   // 8 KB: bel[i0..i0+31][n]
  __shared__ float av_s[16*64];    // 4 KB: a[t][k][n]
  int tid = threadIdx.x, bx = blockIdx.x;
  int jc = bx & 15, ic = bx >> 4;
  int i0 = ic*32, j0 = jc*32;
  *(float4*)&bel_s[tid*4] = *(const float4*)(belT + (size_t)i0*64 + tid*4);
  if (tid < 256) *(float4*)&av_s[tid*4] = *(const float4*)(aT + (size_t)t*1024 + tid*4);
  __syncthreads();
  int n = tid >> 3, jq = tid & 7;
  const float* TrB = Tr + (size_t)i0*SS + j0 + jq*4;
  float4 acc = {0.f, 0.f, 0.f, 0.f};
  for (int k = 0; k < 16; k++) {
    float av = av_s[k*64 + n];
    const float* p = TrB + (size_t)k*SS*SS;
    #pragma unroll 8
    for (int ii = 0; ii < 32; ii++) {
      float bw = av * bel_s[ii*64 + n];
      float4 tv = *(const float4*)(p + (size_t)ii*SS);
      acc.x = fmaf(bw, tv.x, acc.x);
      acc.y = fmaf(bw, tv.y, acc.y);
      acc.z = fmaf(bw, tv.z, acc.z);
      acc.w = fmaf(bw, tv.w, acc.w);
    }
  }
  *(float4*)(partial + ((size_t)ic*64 + n)*SS + j0 + jq*4) = acc;
}

// ---------------- scan phase B: ic-reduce + log + lpo + softmax_j; writes alpha_b[t] + belT carry
__global__ __launch_bounds__(256) void k_step_softmax(const float* __restrict__ partial,
                                                      const float* __restrict__ lpo,
                                                      float* __restrict__ belT,
                                                      float* __restrict__ alpha_b,
                                                      int t) {
  __shared__ float red[256];
  int tid = threadIdx.x, nn = blockIdx.x;
  float sr[2];
  #pragma unroll
  for (int rr = 0; rr < 2; rr++) {
    int j = tid + rr*256;
    float s = 0.f;
    #pragma unroll
    for (int c = 0; c < 16; c++) s += partial[(size_t)c*32768 + nn*512 + j];
    sr[rr] = logf(s + 1e-6f) + lpo[((size_t)t*BB + nn)*SS + j];
  }
  float lm = fmaxf(sr[0], sr[1]);
  red[tid] = lm; __syncthreads();
  for (int s2 = 128; s2 > 0; s2 >>= 1) { if (tid < s2) red[tid] = fmaxf(red[tid], red[tid+s2]); __syncthreads(); }
  float mx = red[0]; __syncthreads();
  float e0 = expf(sr[0]-mx), e1 = expf(sr[1]-mx);
  red[tid] = e0 + e1; __syncthreads();
  for (int s2 = 128; s2 > 0; s2 >>= 1) { if (tid < s2) red[tid] += red[tid+s2]; __syncthreads(); }
  float inv = 1.f/red[0];
  float b0 = e0*inv, b1 = e1*inv;
  size_t ob = ((size_t)t*BB + nn)*SS;
  alpha_b[ob + tid]       = b0;
  alpha_b[ob + tid + 256] = b1;
  belT[(size_t)tid*64 + nn]       = b0;
  belT[(size_t)(tid+256)*64 + nn] = b1;
}

// ---------------- plan() for all T at once: block = (n, 16-t chunk)
__global__ __launch_bounds__(256) void k_pi(const float* __restrict__ alpha_b,
                                            const float* __restrict__ value,
                                            const float* __restrict__ pdf,
                                            float* __restrict__ alpha_pi) {
  __shared__ float Ab_l[16*512];   // 32 KB
  __shared__ float lg[16*256];     // 16 KB
  __shared__ float pi_l[256];
  __shared__ float pdf_l[HH];
  int tid = threadIdx.x, bx = blockIdx.x;
  int n = bx & 63, tc = bx >> 6;   // tc 0..3
  int t0 = tc*16;
  if (tid < HH) pdf_l[tid] = pdf[tid];
  #pragma unroll
  for (int l = 0; l < 32; l++) {
    int idx = l*256 + tid;
    int tt = idx >> 9, i = idx & 511;
    Ab_l[idx] = alpha_b[(((size_t)(t0+tt))*BB + n)*SS + i];
  }
  __syncthreads();
  for (int r = 0; r < 2; r++) {
    int hk = r*256 + tid;
    int h = hk >> 4, k = hk & 15;
    const float* Vrow = value + (((size_t)h*BB + n)*AA + k)*SS;
    float acc[16];
    #pragma unroll
    for (int tt = 0; tt < 16; tt++) acc[tt] = 0.f;
    for (int i = 0; i < SS; i += 4) {
      float4 v4 = *(const float4*)(Vrow + i);
      #pragma unroll
      for (int tt = 0; tt < 16; tt++) {
        float4 ab = *(const float4*)&Ab_l[tt*512 + i];
        acc[tt] = fmaf(v4.x, ab.x, acc[tt]);
        acc[tt] = fmaf(v4.y, ab.y, acc[tt]);
        acc[tt] = fmaf(v4.z, ab.z, acc[tt]);
        acc[tt] = fmaf(v4.w, ab.w, acc[tt]);
      }
    }
    #pragma unroll
    for (int tt = 0; tt < 16; tt++) lg[tt*256 + tid] = acc[tt];
    __syncthreads();
    {
      int tt = tid & 15, hh = tid >> 4;
      int h2 = r*16 + hh;
      float* row = &lg[tt*256 + hh*16];
      float m = row[0];
      #pragma unroll
      for (int k2 = 1; k2 < 16; k2++) m = fmaxf(m, row[k2]);
      float e[16]; float s = 0.f;
      #pragma unroll
      for (int k2 = 0; k2 < 16; k2++) { e[k2] = expf(row[k2]-m); s += e[k2]; }
      float w = pdf_l[h2] / s;
      #pragma unroll
      for (int k2 = 0; k2 < 16; k2++) row[k2] = e[k2]*w;
    }
    __syncthreads();
    {
      int tt = tid >> 4, k2 = tid & 15;
      float s = 0.f;
      #pragma unroll
      for (int hh = 0; hh < 16; hh++) s += lg[tt*256 + hh*16 + k2];
      if (r == 0) pi_l[tid] = s; else pi_l[tid] += s;
    }
    __syncthreads();
  }
  int tt = tid >> 4, k2 = tid & 15;
  alpha_pi[(((size_t)(t0+tt))*BB + n)*AA + k2] = pi_l[tid];
}

extern "C" void kernel_launch(void* const* d_in, const int* in_sizes, int n_in,
                              void* d_out, int out_size, void* d_ws, size_t ws_size,
                              hipStream_t stream) {
  const float* lpo   = (const float*)d_in[0];   // [T,B,S]
  const float* lpu   = (const float*)d_in[1];   // [T,B,A]
  const float* value = (const float*)d_in[2];   // [H,B,A,S]
  const float* b     = (const float*)d_in[3];   // [B,S]
  const float* u     = (const float*)d_in[4];   // [S,R]
  const float* v     = (const float*)d_in[5];   // [A,R]
  const float* tau   = (const float*)d_in[6];   // [1,1]
  float* out = (float*)d_out;
  float* ws  = (float*)d_ws;

  float* Tr      = ws + WS_TR;
  float* aT      = ws + WS_AT;
  float* pdf     = ws + WS_PDF;
  float* belT    = ws + WS_BELT;
  float* partial = ws + WS_PART;

  hipLaunchKernelGGL(k_trans2,  dim3(512), dim3(256), 0, stream, u, v, Tr);
  hipLaunchKernelGGL(k_alpha_a, dim3(16),  dim3(256), 0, stream, lpu, aT);
  hipLaunchKernelGGL(k_taupdf,  dim3(1),   dim3(64),  0, stream, tau, pdf);
  hipLaunchKernelGGL(k_belinit, dim3(128), dim3(256), 0, stream, b, belT);

  float* alpha_b = out;
  for (int t = 0; t < TT; t++) {
    hipLaunchKernelGGL(k_step_gemm,    dim3(256), dim3(512), 0, stream, Tr, aT, belT, partial, t);
    hipLaunchKernelGGL(k_step_softmax, dim3(64),  dim3(256), 0, stream, partial, lpo, belT, alpha_b, t);
  }

  float* alpha_pi = out + (size_t)TT*BB*SS;
  hipLaunchKernelGGL(k_pi, dim3(256), dim3(256), 0, stream, out, value, pdf, alpha_pi);
}

// Round 5
// 1739.405 us; speedup vs baseline: 8.3270x; 1.4617x over previous
//
#include <hip/hip_runtime.h>
#include <cmath>

#define TT 64
#define BB 64
#define SS 512
#define AA 16
#define RR 64
#define HH 32
#define EPS 1e-6f

// ws layout in floats
#define WS_TR   0                         // transition [A][S][S] = 4194304
#define WS_AT   4194304                   // alpha_a transposed [T][A][B] = 65536
#define WS_PDF  (WS_AT + 65536)           // tau_pdf [32]
#define WS_X0   (WS_PDF + 32)             // sigma buf 0 [B][S] = 32768
#define WS_X1   (WS_X0 + 32768)           // sigma buf 1
#define WS_X2   (WS_X1 + 32768)           // sigma buf 2

// ---------------- transition: T[k,i,j] = softmax_j( (u_i - 2 (u_i.vn_k) vn_k) . u_j )
__global__ __launch_bounds__(256) void k_trans2(const float* __restrict__ u,
                                                const float* __restrict__ v,
                                                float* __restrict__ Tr) {
  int bx = blockIdx.x;
  int k = bx >> 5, ic = bx & 31, i0 = ic * 16;
  __shared__ float urot_s[16][68];
  __shared__ float ut_s[64][68];
  __shared__ float w_s[16][516];
  int tid = threadIdx.x;
  int lane = tid & 63, wv = tid >> 6;

  float vkm = v[k*RR + lane];
  float n2 = vkm * vkm;
  #pragma unroll
  for (int o = 32; o > 0; o >>= 1) n2 += __shfl_xor(n2, o, 64);

  #pragma unroll
  for (int r = 0; r < 4; r++) {
    int il = wv*4 + r;
    float um = u[(size_t)(i0 + il)*RR + lane];
    float dt = um * vkm;
    #pragma unroll
    for (int o = 32; o > 0; o >>= 1) dt += __shfl_xor(dt, o, 64);
    urot_s[il][lane] = um - (2.f * dt / n2) * vkm;
  }

  int il = tid >> 4, jl4 = (tid & 15) * 4;
  for (int jt = 0; jt < 8; jt++) {
    __syncthreads();
    #pragma unroll
    for (int q = 0; q < 4; q++) {
      int fi = q*256 + tid;
      int r = fi >> 4, c4 = (fi & 15) * 4;
      float4 uu = *(const float4*)(u + (size_t)(jt*64 + r)*RR + c4);
      ut_s[c4+0][r] = uu.x; ut_s[c4+1][r] = uu.y;
      ut_s[c4+2][r] = uu.z; ut_s[c4+3][r] = uu.w;
    }
    __syncthreads();
    float4 acc = {0.f, 0.f, 0.f, 0.f};
    #pragma unroll 8
    for (int m = 0; m < 64; m++) {
      float ur = urot_s[il][m];
      float4 uu = *(const float4*)&ut_s[m][jl4];
      acc.x = fmaf(ur, uu.x, acc.x);
      acc.y = fmaf(ur, uu.y, acc.y);
      acc.z = fmaf(ur, uu.z, acc.z);
      acc.w = fmaf(ur, uu.w, acc.w);
    }
    *(float4*)&w_s[il][jt*64 + jl4] = acc;
  }
  __syncthreads();

  #pragma unroll
  for (int r = 0; r < 4; r++) {
    int ir = wv*4 + r;
    float vals[8]; float mx = -1e30f;
    #pragma unroll
    for (int q = 0; q < 8; q++) { vals[q] = w_s[ir][q*64 + lane]; mx = fmaxf(mx, vals[q]); }
    #pragma unroll
    for (int o = 32; o > 0; o >>= 1) mx = fmaxf(mx, __shfl_xor(mx, o, 64));
    float sm = 0.f;
    #pragma unroll
    for (int q = 0; q < 8; q++) { vals[q] = expf(vals[q] - mx); sm += vals[q]; }
    #pragma unroll
    for (int o = 32; o > 0; o >>= 1) sm += __shfl_xor(sm, o, 64);
    float inv = 1.f / sm;
    #pragma unroll
    for (int q = 0; q < 8; q++)
      Tr[((size_t)k*SS + (i0 + ir))*SS + q*64 + lane] = vals[q] * inv;
  }
}

// ---------------- alpha_a = softmax(logp_u, -1), stored transposed [T][A][B]
__global__ __launch_bounds__(256) void k_alpha_a(const float* __restrict__ lpu,
                                                 float* __restrict__ aT) {
  int idx = blockIdx.x*256 + threadIdx.x;
  int t = idx >> 6, n = idx & 63;
  const float* x = lpu + (size_t)idx * AA;
  float xs[AA]; float m = -1e30f;
  #pragma unroll
  for (int k = 0; k < AA; k++) { xs[k] = x[k]; m = fmaxf(m, xs[k]); }
  float s = 0.f;
  #pragma unroll
  for (int k = 0; k < AA; k++) { xs[k] = expf(xs[k]-m); s += xs[k]; }
  float inv = 1.f/s;
  #pragma unroll
  for (int k = 0; k < AA; k++) aT[t*(AA*BB) + k*BB + n] = xs[k]*inv;
}

// ---------------- normalized Poisson pmf over k=1..H with rate=softplus(tau)
__global__ void k_taupdf(const float* __restrict__ tau, float* __restrict__ pdf) {
  __shared__ float pl[HH]; __shared__ float ss;
  int tid = threadIdx.x;
  float rate = log1pf(expf(tau[0]));
  if (tid < HH) {
    float kk = (float)(tid+1);
    pl[tid] = expf(kk*logf(rate) - rate - lgammaf(kk+1.f));
  }
  __syncthreads();
  if (tid == 0) { float s = 0.f; for (int h = 0; h < HH; h++) s += pl[h]; ss = 1.f/s; }
  __syncthreads();
  if (tid < HH) pdf[tid] = pl[tid]*ss;
}

// ---------------- zero the sigma accumulator buffers
__global__ __launch_bounds__(256) void k_zero(float* __restrict__ X1,
                                              float* __restrict__ X2) {
  int idx = blockIdx.x*256 + threadIdx.x;   // < 32768
  X1[idx] = 0.f; X2[idx] = 0.f;
}

// ---------------- fused scan step (ONE dispatch per t)
// Carry: X[t%3] = sigma_{t-1}[n][j] (unnormalized pre-obs state), X[(t+1)%3] = atomic accum target.
// bel_{t-1}[n,i] = (sigma_{t-1}[n,i]+eps)*exp(lpo[t-1][n,i]) / G[n]   (t=0: bel = b directly)
// grid 256 blocks (ic 16 x jc 16), 512 threads: jq=tid&7 (4 j), ii=(tid>>3)&7, nq=tid>>6 (8 n)
__global__ __launch_bounds__(512) void k_step(const float* __restrict__ Tr,
                                              const float* __restrict__ aT,
                                              const float* __restrict__ lpo,
                                              const float* __restrict__ b,
                                              float* __restrict__ X0,
                                              float* __restrict__ X1,
                                              float* __restrict__ X2,
                                              float* __restrict__ alpha_b,
                                              int t) {
  __shared__ float bel_s[32*64];    // bel slice [il][n]
  __shared__ float a_s[16*64];      // a[t][k][n]
  __shared__ float invG_l[64];
  int tid = threadIdx.x, bx = blockIdx.x;
  int jc = bx & 15, ic = bx >> 4;
  int i0 = ic*32, j0 = jc*32;

  const float* Xr; float* Xw; float* Xz;
  {
    int r = t % 3;
    if (r == 0)      { Xr = X0; Xw = X1; Xz = X2; }
    else if (r == 1) { Xr = X1; Xw = X2; Xz = X0; }
    else             { Xr = X2; Xw = X0; Xz = X1; }
  }
  const float* S = (t == 0) ? b : Xr;      // [n][j]
  const float* lpoPrev = lpo + (size_t)(t-1)*BB*SS;   // valid for t>=1

  // zero next-next buffer (untouched by any read/write this step)
  { int g = bx*512 + tid; if (g < 32768) Xz[g] = 0.f; }

  // ---- pass 1: G[n] = sum_j (S[n,j]+eps)*exp(lpo[t-1][n,j])  (skip at t=0: G=1)
  if (t > 0) {
    int jcl = tid & 7, n = tid >> 3;   // n 0..63, 8 j-lanes each
    float g = 0.f;
    #pragma unroll 8
    for (int q = 0; q < 64; q++) {
      int j = q*8 + jcl;
      size_t off = (size_t)n*SS + j;
      g += (S[off] + EPS) * expf(lpoPrev[off]);
    }
    g += __shfl_xor(g, 1, 64); g += __shfl_xor(g, 2, 64); g += __shfl_xor(g, 4, 64);
    if (jcl == 0) invG_l[n] = 1.f / g;
  }
  __syncthreads();

  // ---- pass 2: bel_s[il][n] for i-slice; stage a_s
  #pragma unroll
  for (int q = 0; q < 4; q++) {
    int idx = q*512 + tid;            // 0..2047
    int nn = idx >> 5, il = idx & 31;
    size_t off = (size_t)nn*SS + i0 + il;
    float val;
    if (t == 0) val = S[off];
    else        val = (S[off] + EPS) * expf(lpoPrev[off]) * invG_l[nn];
    bel_s[il*64 + nn] = val;
  }
  if (tid < 256) *(float4*)&a_s[tid*4] = *(const float4*)(aT + (size_t)t*1024 + tid*4);

  // ---- alpha_b[t-1] slice (blocks with ic==jc; coalesced)
  if (t > 0 && ic == jc) {
    #pragma unroll
    for (int q = 0; q < 4; q++) {
      int idx = q*512 + tid;
      int nn = idx >> 5, il = idx & 31;
      size_t off = (size_t)nn*SS + i0 + il;
      float val = (S[off] + EPS) * expf(lpoPrev[off]) * invG_l[nn];
      alpha_b[((size_t)(t-1)*BB + nn)*SS + i0 + il] = val;
    }
  }
  __syncthreads();

  // ---- GEMM: acc[m](j4) += a[k,n]*bel[i,n]*Tr[k,i,j]
  int jq = tid & 7, ii = (tid >> 3) & 7, nq = tid >> 6;
  int n0 = nq*8;
  float4 acc[8];
  #pragma unroll
  for (int m = 0; m < 8; m++) acc[m] = make_float4(0.f, 0.f, 0.f, 0.f);
  const float* TrBase = Tr + (size_t)(i0 + ii)*SS + j0 + jq*4;

  for (int kb = 0; kb < 4; kb++) {
    float af[4][8];
    #pragma unroll
    for (int kk = 0; kk < 4; kk++) {
      *(float4*)&af[kk][0] = *(float4*)&a_s[(kb*4+kk)*64 + n0];
      *(float4*)&af[kk][4] = *(float4*)&a_s[(kb*4+kk)*64 + n0 + 4];
    }
    #pragma unroll
    for (int io = 0; io < 4; io++) {
      float bf[8];
      *(float4*)&bf[0] = *(float4*)&bel_s[(io*8+ii)*64 + n0];
      *(float4*)&bf[4] = *(float4*)&bel_s[(io*8+ii)*64 + n0 + 4];
      #pragma unroll
      for (int kk = 0; kk < 4; kk++) {
        float4 tv = *(const float4*)(TrBase + ((size_t)(kb*4+kk)*SS + io*8)*SS);
        #pragma unroll
        for (int m = 0; m < 8; m++) {
          float w = af[kk][m] * bf[m];
          acc[m].x = fmaf(w, tv.x, acc[m].x);
          acc[m].y = fmaf(w, tv.y, acc[m].y);
          acc[m].z = fmaf(w, tv.z, acc[m].z);
          acc[m].w = fmaf(w, tv.w, acc[m].w);
        }
      }
    }
  }

  // ---- reduce over ii lanes (bits 3..5), then atomic-accumulate into Xw[n][j]
  #pragma unroll
  for (int m = 0; m < 8; m++) {
    #pragma unroll
    for (int o = 8; o <= 32; o <<= 1) {
      acc[m].x += __shfl_xor(acc[m].x, o, 64);
      acc[m].y += __shfl_xor(acc[m].y, o, 64);
      acc[m].z += __shfl_xor(acc[m].z, o, 64);
      acc[m].w += __shfl_xor(acc[m].w, o, 64);
    }
  }
  if (ii == 0) {
    #pragma unroll
    for (int m = 0; m < 8; m++) {
      float* dst = Xw + (size_t)(n0+m)*SS + j0 + jq*4;
      atomicAdd(dst+0, acc[m].x);
      atomicAdd(dst+1, acc[m].y);
      atomicAdd(dst+2, acc[m].z);
      atomicAdd(dst+3, acc[m].w);
    }
  }
}

// ---------------- final belief (t=63): alpha_b[63][n][j] from X[64%3=1]
__global__ __launch_bounds__(512) void k_lastbel(const float* __restrict__ X,
                                                 const float* __restrict__ lpo,
                                                 float* __restrict__ alpha_b) {
  __shared__ float red[512];
  int n = blockIdx.x, j = threadIdx.x;
  size_t off = (size_t)n*SS + j;
  float g = (X[off] + EPS) * expf(lpo[((size_t)63*BB + n)*SS + j]);
  red[j] = g; __syncthreads();
  for (int s = 256; s > 0; s >>= 1) { if (j < s) red[j] += red[j+s]; __syncthreads(); }
  float inv = 1.f / red[0];
  alpha_b[((size_t)63*BB + n)*SS + j] = g * inv;
}

// ---------------- plan() for all T at once: block = (n, 16-t chunk)
__global__ __launch_bounds__(256) void k_pi(const float* __restrict__ alpha_b,
                                            const float* __restrict__ value,
                                            const float* __restrict__ pdf,
                                            float* __restrict__ alpha_pi) {
  __shared__ float Ab_l[16*512];
  __shared__ float lg[16*256];
  __shared__ float pi_l[256];
  __shared__ float pdf_l[HH];
  int tid = threadIdx.x, bx = blockIdx.x;
  int n = bx & 63, tc = bx >> 6;
  int t0 = tc*16;
  if (tid < HH) pdf_l[tid] = pdf[tid];
  #pragma unroll
  for (int l = 0; l < 32; l++) {
    int idx = l*256 + tid;
    int tt = idx >> 9, i = idx & 511;
    Ab_l[idx] = alpha_b[(((size_t)(t0+tt))*BB + n)*SS + i];
  }
  __syncthreads();
  for (int r = 0; r < 2; r++) {
    int hk = r*256 + tid;
    int h = hk >> 4, k = hk & 15;
    const float* Vrow = value + (((size_t)h*BB + n)*AA + k)*SS;
    float acc[16];
    #pragma unroll
    for (int tt = 0; tt < 16; tt++) acc[tt] = 0.f;
    for (int i = 0; i < SS; i += 4) {
      float4 v4 = *(const float4*)(Vrow + i);
      #pragma unroll
      for (int tt = 0; tt < 16; tt++) {
        float4 ab = *(const float4*)&Ab_l[tt*512 + i];
        acc[tt] = fmaf(v4.x, ab.x, acc[tt]);
        acc[tt] = fmaf(v4.y, ab.y, acc[tt]);
        acc[tt] = fmaf(v4.z, ab.z, acc[tt]);
        acc[tt] = fmaf(v4.w, ab.w, acc[tt]);
      }
    }
    #pragma unroll
    for (int tt = 0; tt < 16; tt++) lg[tt*256 + tid] = acc[tt];
    __syncthreads();
    {
      int tt = tid & 15, hh = tid >> 4;
      int h2 = r*16 + hh;
      float* row = &lg[tt*256 + hh*16];
      float m = row[0];
      #pragma unroll
      for (int k2 = 1; k2 < 16; k2++) m = fmaxf(m, row[k2]);
      float e[16]; float s = 0.f;
      #pragma unroll
      for (int k2 = 0; k2 < 16; k2++) { e[k2] = expf(row[k2]-m); s += e[k2]; }
      float w = pdf_l[h2] / s;
      #pragma unroll
      for (int k2 = 0; k2 < 16; k2++) row[k2] = e[k2]*w;
    }
    __syncthreads();
    {
      int tt = tid >> 4, k2 = tid & 15;
      float s = 0.f;
      #pragma unroll
      for (int hh = 0; hh < 16; hh++) s += lg[tt*256 + hh*16 + k2];
      if (r == 0) pi_l[tid] = s; else pi_l[tid] += s;
    }
    __syncthreads();
  }
  int tt = tid >> 4, k2 = tid & 15;
  alpha_pi[(((size_t)(t0+tt))*BB + n)*AA + k2] = pi_l[tid];
}

extern "C" void kernel_launch(void* const* d_in, const int* in_sizes, int n_in,
                              void* d_out, int out_size, void* d_ws, size_t ws_size,
                              hipStream_t stream) {
  const float* lpo   = (const float*)d_in[0];   // [T,B,S]
  const float* lpu   = (const float*)d_in[1];   // [T,B,A]
  const float* value = (const float*)d_in[2];   // [H,B,A,S]
  const float* b     = (const float*)d_in[3];   // [B,S]
  const float* u     = (const float*)d_in[4];   // [S,R]
  const float* v     = (const float*)d_in[5];   // [A,R]
  const float* tau   = (const float*)d_in[6];   // [1,1]
  float* out = (float*)d_out;
  float* ws  = (float*)d_ws;

  float* Tr  = ws + WS_TR;
  float* aT  = ws + WS_AT;
  float* pdf = ws + WS_PDF;
  float* X0  = ws + WS_X0;
  float* X1  = ws + WS_X1;
  float* X2  = ws + WS_X2;

  hipLaunchKernelGGL(k_trans2,  dim3(512), dim3(256), 0, stream, u, v, Tr);
  hipLaunchKernelGGL(k_alpha_a, dim3(16),  dim3(256), 0, stream, lpu, aT);
  hipLaunchKernelGGL(k_taupdf,  dim3(1),   dim3(64),  0, stream, tau, pdf);
  hipLaunchKernelGGL(k_zero,    dim3(128), dim3(256), 0, stream, X1, X2);

  float* alpha_b = out;
  for (int t = 0; t < TT; t++) {
    hipLaunchKernelGGL(k_step, dim3(256), dim3(512), 0, stream,
                       Tr, aT, lpo, b, X0, X1, X2, alpha_b, t);
  }
  hipLaunchKernelGGL(k_lastbel, dim3(64), dim3(512), 0, stream, X1, lpo, alpha_b);

  float* alpha_pi = out + (size_t)TT*BB*SS;
  hipLaunchKernelGGL(k_pi, dim3(256), dim3(256), 0, stream, out, value, pdf, alpha_pi);
}

// Round 6
// 1710.143 us; speedup vs baseline: 8.4695x; 1.0171x over previous
//
#include <hip/hip_runtime.h>
#include <cmath>

#define TT 64
#define BB 64
#define SS 512
#define AA 16
#define RR 64
#define HH 32
#define EPS 1e-6f

// ws layout in floats
#define WS_TR   0                         // transition [A][S][S] = 4194304
#define WS_AT   4194304                   // alpha_a transposed [T][A][B] = 65536
#define WS_PDF  (WS_AT + 65536)           // tau_pdf [32]
#define WS_X0   (WS_PDF + 32)             // sigma buf 0 [B][S] = 32768
#define WS_X1   (WS_X0 + 32768)           // sigma buf 1
#define WS_X2   (WS_X1 + 32768)           // sigma buf 2
#define WS_BAR  (WS_X2 + 32768)           // barrier region (1024 uints)

#define AGENT __HIP_MEMORY_SCOPE_AGENT

__device__ __forceinline__ float aload(const float* p) {
  return __hip_atomic_load(p, __ATOMIC_RELAXED, AGENT);
}
__device__ __forceinline__ void astore(float* p, float v) {
  __hip_atomic_store(p, v, __ATOMIC_RELAXED, AGENT);
}

// ---------------- transition
__global__ __launch_bounds__(256) void k_trans2(const float* __restrict__ u,
                                                const float* __restrict__ v,
                                                float* __restrict__ Tr) {
  int bx = blockIdx.x;
  int k = bx >> 5, ic = bx & 31, i0 = ic * 16;
  __shared__ float urot_s[16][68];
  __shared__ float ut_s[64][68];
  __shared__ float w_s[16][516];
  int tid = threadIdx.x;
  int lane = tid & 63, wv = tid >> 6;

  float vkm = v[k*RR + lane];
  float n2 = vkm * vkm;
  #pragma unroll
  for (int o = 32; o > 0; o >>= 1) n2 += __shfl_xor(n2, o, 64);

  #pragma unroll
  for (int r = 0; r < 4; r++) {
    int il = wv*4 + r;
    float um = u[(size_t)(i0 + il)*RR + lane];
    float dt = um * vkm;
    #pragma unroll
    for (int o = 32; o > 0; o >>= 1) dt += __shfl_xor(dt, o, 64);
    urot_s[il][lane] = um - (2.f * dt / n2) * vkm;
  }

  int il = tid >> 4, jl4 = (tid & 15) * 4;
  for (int jt = 0; jt < 8; jt++) {
    __syncthreads();
    #pragma unroll
    for (int q = 0; q < 4; q++) {
      int fi = q*256 + tid;
      int r = fi >> 4, c4 = (fi & 15) * 4;
      float4 uu = *(const float4*)(u + (size_t)(jt*64 + r)*RR + c4);
      ut_s[c4+0][r] = uu.x; ut_s[c4+1][r] = uu.y;
      ut_s[c4+2][r] = uu.z; ut_s[c4+3][r] = uu.w;
    }
    __syncthreads();
    float4 acc = {0.f, 0.f, 0.f, 0.f};
    #pragma unroll 8
    for (int m = 0; m < 64; m++) {
      float ur = urot_s[il][m];
      float4 uu = *(const float4*)&ut_s[m][jl4];
      acc.x = fmaf(ur, uu.x, acc.x);
      acc.y = fmaf(ur, uu.y, acc.y);
      acc.z = fmaf(ur, uu.z, acc.z);
      acc.w = fmaf(ur, uu.w, acc.w);
    }
    *(float4*)&w_s[il][jt*64 + jl4] = acc;
  }
  __syncthreads();

  #pragma unroll
  for (int r = 0; r < 4; r++) {
    int ir = wv*4 + r;
    float vals[8]; float mx = -1e30f;
    #pragma unroll
    for (int q = 0; q < 8; q++) { vals[q] = w_s[ir][q*64 + lane]; mx = fmaxf(mx, vals[q]); }
    #pragma unroll
    for (int o = 32; o > 0; o >>= 1) mx = fmaxf(mx, __shfl_xor(mx, o, 64));
    float sm = 0.f;
    #pragma unroll
    for (int q = 0; q < 8; q++) { vals[q] = expf(vals[q] - mx); sm += vals[q]; }
    #pragma unroll
    for (int o = 32; o > 0; o >>= 1) sm += __shfl_xor(sm, o, 64);
    float inv = 1.f / sm;
    #pragma unroll
    for (int q = 0; q < 8; q++)
      Tr[((size_t)k*SS + (i0 + ir))*SS + q*64 + lane] = vals[q] * inv;
  }
}

// ---------------- alpha_a transposed [T][A][B]
__global__ __launch_bounds__(256) void k_alpha_a(const float* __restrict__ lpu,
                                                 float* __restrict__ aT) {
  int idx = blockIdx.x*256 + threadIdx.x;
  int t = idx >> 6, n = idx & 63;
  const float* x = lpu + (size_t)idx * AA;
  float xs[AA]; float m = -1e30f;
  #pragma unroll
  for (int k = 0; k < AA; k++) { xs[k] = x[k]; m = fmaxf(m, xs[k]); }
  float s = 0.f;
  #pragma unroll
  for (int k = 0; k < AA; k++) { xs[k] = expf(xs[k]-m); s += xs[k]; }
  float inv = 1.f/s;
  #pragma unroll
  for (int k = 0; k < AA; k++) aT[t*(AA*BB) + k*BB + n] = xs[k]*inv;
}

// ---------------- Poisson pdf
__global__ void k_taupdf(const float* __restrict__ tau, float* __restrict__ pdf) {
  __shared__ float pl[HH]; __shared__ float ss;
  int tid = threadIdx.x;
  float rate = log1pf(expf(tau[0]));
  if (tid < HH) {
    float kk = (float)(tid+1);
    pl[tid] = expf(kk*logf(rate) - rate - lgammaf(kk+1.f));
  }
  __syncthreads();
  if (tid == 0) { float s = 0.f; for (int h = 0; h < HH; h++) s += pl[h]; ss = 1.f/s; }
  __syncthreads();
  if (tid < HH) pdf[tid] = pl[tid]*ss;
}

// ---------------- zero X1/X2, barrier region, alpha_pi
__global__ __launch_bounds__(256) void k_zero(float* __restrict__ X1,
                                              float* __restrict__ X2,
                                              unsigned* __restrict__ bar,
                                              float* __restrict__ alpha_pi) {
  int idx = blockIdx.x*256 + threadIdx.x;   // grid 256*256 = 65536
  if (idx < 32768) { X1[idx] = 0.f; X2[idx] = 0.f; }
  if (idx < 1024) bar[idx] = 0u;
  alpha_pi[idx] = 0.f;                      // 65536 floats
}

// ---------------- persistent scan: 256 blocks x 512 thr, hierarchical barrier
// block = (jc = bx&15 [32 j], ic = bx>>4 [32 i]); per-XCD-group g = bx&7
// barrier layout (uints): [g*32] arrival counters; [256] global counter; [288+g*32] release
__global__ __launch_bounds__(512) void k_scan(const float* __restrict__ Tr,
                                              const float* __restrict__ aT,
                                              const float* __restrict__ lpo,
                                              const float* __restrict__ b,
                                              float* __restrict__ X0,
                                              float* __restrict__ X1,
                                              float* __restrict__ X2,
                                              float* __restrict__ alpha_b,
                                              unsigned* __restrict__ bar) {
  __shared__ float bel_s[32*64];
  __shared__ float a_s[16*64];
  __shared__ float invG_l[64];
  int tid = threadIdx.x, bx = blockIdx.x;
  int jc = bx & 15, ic = bx >> 4;
  int i0 = ic*32, j0 = jc*32;
  int g = bx & 7;
  unsigned* arr = bar + g*32;
  unsigned* gcnt = bar + 256;
  unsigned* rel = bar + 288 + g*32;

  for (int t = 0; t < TT; t++) {
    const float* Xr; float* Xw; float* Xz;
    {
      int r = t % 3;
      if (r == 0)      { Xr = X0; Xw = X1; Xz = X2; }
      else if (r == 1) { Xr = X1; Xw = X2; Xz = X0; }
      else             { Xr = X2; Xw = X0; Xz = X1; }
    }
    const float* lpoPrev = lpo + (size_t)(t-1)*BB*SS;

    // zero next-next buffer (nobody reads/writes it this step)
    { int g2 = bx*512 + tid; if (g2 < 32768) astore(Xz + g2, 0.f); }

    // pass 1: invG[n] (t>0)
    if (t > 0) {
      int jcl = tid & 7, n = tid >> 3;
      float gg = 0.f;
      #pragma unroll 8
      for (int q = 0; q < 64; q++) {
        int j = q*8 + jcl;
        size_t off = (size_t)n*SS + j;
        gg += (aload(Xr + off) + EPS) * expf(lpoPrev[off]);
      }
      gg += __shfl_xor(gg, 1, 64); gg += __shfl_xor(gg, 2, 64); gg += __shfl_xor(gg, 4, 64);
      if (jcl == 0) invG_l[n] = 1.f / gg;
    }
    __syncthreads();

    // pass 2: bel_s slice + a_s stage (+ alpha_b[t-1] on diagonal blocks)
    if (t == 0) {
      #pragma unroll
      for (int q = 0; q < 4; q++) {
        int idx = q*512 + tid;
        int nn = idx >> 5, il = idx & 31;
        bel_s[il*64 + nn] = b[(size_t)nn*SS + i0 + il];
      }
    } else {
      #pragma unroll
      for (int q = 0; q < 4; q++) {
        int idx = q*512 + tid;
        int nn = idx >> 5, il = idx & 31;
        size_t off = (size_t)nn*SS + i0 + il;
        float val = (aload(Xr + off) + EPS) * expf(lpoPrev[off]) * invG_l[nn];
        bel_s[il*64 + nn] = val;
        if (ic == jc) astore(alpha_b + ((size_t)(t-1)*BB + nn)*SS + i0 + il, val);
      }
    }
    if (tid < 256) *(float4*)&a_s[tid*4] = *(const float4*)(aT + (size_t)t*1024 + tid*4);
    __syncthreads();

    // GEMM
    int jq = tid & 7, ii = (tid >> 3) & 7, nq = tid >> 6;
    int n0 = nq*8;
    float4 acc[8];
    #pragma unroll
    for (int m = 0; m < 8; m++) acc[m] = make_float4(0.f, 0.f, 0.f, 0.f);
    const float* TrBase = Tr + (size_t)(i0 + ii)*SS + j0 + jq*4;

    for (int kb = 0; kb < 4; kb++) {
      float af[4][8];
      #pragma unroll
      for (int kk = 0; kk < 4; kk++) {
        *(float4*)&af[kk][0] = *(float4*)&a_s[(kb*4+kk)*64 + n0];
        *(float4*)&af[kk][4] = *(float4*)&a_s[(kb*4+kk)*64 + n0 + 4];
      }
      #pragma unroll
      for (int io = 0; io < 4; io++) {
        float bf[8];
        *(float4*)&bf[0] = *(float4*)&bel_s[(io*8+ii)*64 + n0];
        *(float4*)&bf[4] = *(float4*)&bel_s[(io*8+ii)*64 + n0 + 4];
        #pragma unroll
        for (int kk = 0; kk < 4; kk++) {
          float4 tv = *(const float4*)(TrBase + ((size_t)(kb*4+kk)*SS + io*8)*SS);
          #pragma unroll
          for (int m = 0; m < 8; m++) {
            float w = af[kk][m] * bf[m];
            acc[m].x = fmaf(w, tv.x, acc[m].x);
            acc[m].y = fmaf(w, tv.y, acc[m].y);
            acc[m].z = fmaf(w, tv.z, acc[m].z);
            acc[m].w = fmaf(w, tv.w, acc[m].w);
          }
        }
      }
    }

    #pragma unroll
    for (int m = 0; m < 8; m++) {
      #pragma unroll
      for (int o = 8; o <= 32; o <<= 1) {
        acc[m].x += __shfl_xor(acc[m].x, o, 64);
        acc[m].y += __shfl_xor(acc[m].y, o, 64);
        acc[m].z += __shfl_xor(acc[m].z, o, 64);
        acc[m].w += __shfl_xor(acc[m].w, o, 64);
      }
    }
    if (ii == 0) {
      #pragma unroll
      for (int m = 0; m < 8; m++) {
        float* dst = Xw + (size_t)(n0+m)*SS + j0 + jq*4;
        atomicAdd(dst+0, acc[m].x);
        atomicAdd(dst+1, acc[m].y);
        atomicAdd(dst+2, acc[m].z);
        atomicAdd(dst+3, acc[m].w);
      }
    }

    // hierarchical barrier, epoch e = t+1 (monotonic counters, no reset)
    __syncthreads();
    if (tid == 0) {
      unsigned e = (unsigned)(t + 1);
      unsigned np = __hip_atomic_fetch_add(arr, 1u, __ATOMIC_RELEASE, AGENT);
      if (np == e*32u - 1u) {                       // last arrival of this group
        unsigned gp = __hip_atomic_fetch_add(gcnt, 1u, __ATOMIC_RELEASE, AGENT);
        if (gp == e*8u - 1u) {                      // last group: broadcast release
          #pragma unroll
          for (int g2 = 0; g2 < 8; g2++)
            __hip_atomic_store(bar + 288 + g2*32, e, __ATOMIC_RELAXED, AGENT);
        }
      }
      while (__hip_atomic_load(rel, __ATOMIC_RELAXED, AGENT) < e)
        __builtin_amdgcn_s_sleep(1);
      __atomic_signal_fence(__ATOMIC_ACQUIRE);
    }
    __syncthreads();
  }
}

// ---------------- final belief (t=63) from X1
__global__ __launch_bounds__(512) void k_lastbel(const float* __restrict__ X,
                                                 const float* __restrict__ lpo,
                                                 float* __restrict__ alpha_b) {
  __shared__ float red[512];
  int n = blockIdx.x, j = threadIdx.x;
  size_t off = (size_t)n*SS + j;
  float g = (X[off] + EPS) * expf(lpo[((size_t)63*BB + n)*SS + j]);
  red[j] = g; __syncthreads();
  for (int s = 256; s > 0; s >>= 1) { if (j < s) red[j] += red[j+s]; __syncthreads(); }
  float inv = 1.f / red[0];
  alpha_b[((size_t)63*BB + n)*SS + j] = g * inv;
}

// ---------------- plan(): 512 blocks (n x hk-eighth) x 256 thr, 8t x 2hk reg tile
__global__ __launch_bounds__(256) void k_pi(const float* __restrict__ alpha_b,
                                            const float* __restrict__ value,
                                            const float* __restrict__ pdf,
                                            float* __restrict__ alpha_pi) {
  __shared__ float Ab_l[64][132];   // i-tile of 128, pad 4
  __shared__ float lg[64][68];      // logits [t][hk_local 64]
  __shared__ float pdf_l[HH];
  int tid = threadIdx.x, bx = blockIdx.x;
  int n = bx >> 3, e = bx & 7;
  if (tid < HH) pdf_l[tid] = pdf[tid];
  int hkg = tid >> 3, tg = tid & 7;
  int hk0 = e*64 + hkg*2;
  const float* V0 = value + (((size_t)(hk0    >> 4)*BB + n)*AA + (hk0     & 15))*SS;
  const float* V1 = value + (((size_t)((hk0+1) >> 4)*BB + n)*AA + ((hk0+1) & 15))*SS;

  float4 a0[8], a1[8];
  #pragma unroll
  for (int m = 0; m < 8; m++) { a0[m] = make_float4(0,0,0,0); a1[m] = make_float4(0,0,0,0); }

  for (int it = 0; it < 4; it++) {
    __syncthreads();
    #pragma unroll
    for (int q = 0; q < 8; q++) {
      int idx = q*256 + tid;
      int tt = idx >> 5, il4 = (idx & 31)*4;
      float4 ab = *(const float4*)(alpha_b + ((size_t)tt*BB + n)*SS + it*128 + il4);
      *(float4*)&Ab_l[tt][il4] = ab;
    }
    __syncthreads();
    #pragma unroll 4
    for (int iq = 0; iq < 32; iq++) {
      float4 v0 = *(const float4*)(V0 + it*128 + iq*4);
      float4 v1 = *(const float4*)(V1 + it*128 + iq*4);
      #pragma unroll
      for (int tt = 0; tt < 8; tt++) {
        float4 ab = *(const float4*)&Ab_l[tt*8 + tg][iq*4];
        a0[tt].x = fmaf(ab.x, v0.x, a0[tt].x);
        a0[tt].y = fmaf(ab.y, v0.y, a0[tt].y);
        a0[tt].z = fmaf(ab.z, v0.z, a0[tt].z);
        a0[tt].w = fmaf(ab.w, v0.w, a0[tt].w);
        a1[tt].x = fmaf(ab.x, v1.x, a1[tt].x);
        a1[tt].y = fmaf(ab.y, v1.y, a1[tt].y);
        a1[tt].z = fmaf(ab.z, v1.z, a1[tt].z);
        a1[tt].w = fmaf(ab.w, v1.w, a1[tt].w);
      }
    }
  }
  #pragma unroll
  for (int tt = 0; tt < 8; tt++) {
    lg[tt*8 + tg][hkg*2 + 0] = a0[tt].x + a0[tt].y + a0[tt].z + a0[tt].w;
    lg[tt*8 + tg][hkg*2 + 1] = a1[tt].x + a1[tt].y + a1[tt].z + a1[tt].w;
  }
  __syncthreads();

  // softmax over k for (t, local h): 64t x 4h = 256 threads
  {
    int t = tid >> 2, hh = tid & 3;
    float* row = &lg[t][hh*16];
    float m = row[0];
    #pragma unroll
    for (int k2 = 1; k2 < 16; k2++) m = fmaxf(m, row[k2]);
    float ex[16]; float s = 0.f;
    #pragma unroll
    for (int k2 = 0; k2 < 16; k2++) { ex[k2] = expf(row[k2]-m); s += ex[k2]; }
    float w = pdf_l[e*4 + hh] / s;
    #pragma unroll
    for (int k2 = 0; k2 < 16; k2++) row[k2] = ex[k2]*w;
  }
  __syncthreads();

  // combine 4 local h and atomic into alpha_pi
  #pragma unroll
  for (int q = 0; q < 4; q++) {
    int idx = q*256 + tid;           // 1024 = 64t x 16k
    int t = idx >> 4, k2 = idx & 15;
    float s = lg[t][0*16+k2] + lg[t][1*16+k2] + lg[t][2*16+k2] + lg[t][3*16+k2];
    atomicAdd(alpha_pi + ((size_t)t*BB + n)*AA + k2, s);
  }
}

extern "C" void kernel_launch(void* const* d_in, const int* in_sizes, int n_in,
                              void* d_out, int out_size, void* d_ws, size_t ws_size,
                              hipStream_t stream) {
  const float* lpo   = (const float*)d_in[0];
  const float* lpu   = (const float*)d_in[1];
  const float* value = (const float*)d_in[2];
  const float* b     = (const float*)d_in[3];
  const float* u     = (const float*)d_in[4];
  const float* v     = (const float*)d_in[5];
  const float* tau   = (const float*)d_in[6];
  float* out = (float*)d_out;
  float* ws  = (float*)d_ws;

  float* Tr  = ws + WS_TR;
  float* aT  = ws + WS_AT;
  float* pdf = ws + WS_PDF;
  float* X0  = ws + WS_X0;
  float* X1  = ws + WS_X1;
  float* X2  = ws + WS_X2;
  unsigned* bar = (unsigned*)(ws + WS_BAR);

  float* alpha_b  = out;
  float* alpha_pi = out + (size_t)TT*BB*SS;

  hipLaunchKernelGGL(k_trans2,  dim3(512), dim3(256), 0, stream, u, v, Tr);
  hipLaunchKernelGGL(k_alpha_a, dim3(16),  dim3(256), 0, stream, lpu, aT);
  hipLaunchKernelGGL(k_taupdf,  dim3(1),   dim3(64),  0, stream, tau, pdf);
  hipLaunchKernelGGL(k_zero,    dim3(256), dim3(256), 0, stream, X1, X2, bar, alpha_pi);

  void* args[9];
  args[0] = (void*)&Tr;  args[1] = (void*)&aT;  args[2] = (void*)&lpo;
  args[3] = (void*)&b;   args[4] = (void*)&X0;  args[5] = (void*)&X1;
  args[6] = (void*)&X2;  args[7] = (void*)&alpha_b; args[8] = (void*)&bar;
  hipLaunchCooperativeKernel(k_scan, dim3(256), dim3(512), args, 0, stream);

  hipLaunchKernelGGL(k_lastbel, dim3(64), dim3(512), 0, stream, X1, lpo, alpha_b);
  hipLaunchKernelGGL(k_pi, dim3(512), dim3(256), 0, stream, alpha_b, value, pdf, alpha_pi);
}